// Round 9
// baseline (508.665 us; speedup 1.0000x reference)
//
#include <hip/hip_runtime.h>

// ---------------------------------------------------------------------------
// LocalGlobalBlock on MI355X.  (R11: drop zbuf — it overlapped gpwbf and
// corrupted the 1x1 weights in R9/R10.  Ring-3 counted-vmcnt k_ds kept;
// zh0 zero-padding now via prologue half-0 zeroing + dummy DMA slots.)
//   k_prep : fold BN1/BN2 + biases into (alpha,beta); gpw -> bf16; zero pooled
//   k_wds  : ds_w -> wds2 bf16 LINEAR [kt][oc][64ch]  (A read direct by k_ds)
//   k_xt   : x NCHW fp32 -> xT NHWC bf16 (in d_out; exact fit) + fused pool
//   k_kgen : relu((pooled_sum/HW) @ W_kg^T) -> kgen[16][9][128]  (tap-major)
//   k_dw   : BOTH depthwise stencils (br=0 local dil1, br=1 global dil2)
//   k_pw   : per (b,h): DMA P slabs comb->LDS, 1x1 MFMA + BN1 + ReLU in place
//   k_ds   : downsample 3x3 s2 implicit GEMM, 128oc x 128n, BK=64.
//            B: ring-3 LDS buffers, staged 2 tiles ahead, EXACTLY 4 DMA/wave/
//            tile (dummies -> ldummy keep the count static); A: direct
//            global->reg, prefetched 1 tile ahead.  Loop sync: raw s_barrier
//            + asm s_waitcnt vmcnt(12) (never 0 inside the loop).
//
// comb layout: [b][h][p][icc4][w2 56][64ch], w = 2*w2+p; chunk c (16B=8ch)
// stored at position c^(w2&7) -> DMA deposits a conflict-free LDS image.
// ---------------------------------------------------------------------------

#define DEVI static __device__ __forceinline__

using bf16x8 = __attribute__((ext_vector_type(8))) short;  // 8 bf16 (4 VGPRs)
using f32x4  = __attribute__((ext_vector_type(4))) float;  // MFMA accumulator
typedef unsigned short ushort_t;

constexpr int Bn = 16, MID = 128, CHN = 256, Hh = 112, Wn = 112;
constexpr int OHn = 56, OWn = 56, OCn = 512;
constexpr int HW  = Hh * Wn;        // 12544
constexpr float EPSf = 1e-5f;

// comb strides in ushorts
constexpr size_t C_I = 56 * 64;          // 3584  (per icc)
constexpr size_t C_P = 4 * C_I;          // 14336 (per parity)
constexpr size_t C_H = 2 * C_P;          // 28672 (per h row)
constexpr size_t C_B = (size_t)Hh * C_H; // 3211264 (per batch)

DEVI ushort_t f2b(float f) {  // fp32 -> bf16 RNE (finite data only)
    unsigned u = __float_as_uint(f);
    return (ushort_t)((u + 0x7FFFu + ((u >> 16) & 1u)) >> 16);
}
DEVI float b2f(ushort_t s) { return __uint_as_float(((unsigned)s) << 16); }
DEVI int pack2(float a, float b) {
    return (int)f2b(a) | ((int)f2b(b) << 16);
}

DEVI void gl_lds16(const void* g, void* l) {   // async global->LDS, 16B/lane
    __builtin_amdgcn_global_load_lds(
        (const __attribute__((address_space(1))) unsigned int*)g,
        (__attribute__((address_space(3))) unsigned int*)l, 16, 0, 0);
}

// ------------------------- k_prep ------------------------------------------
__global__ __launch_bounds__(256) void k_prep(
        const float* __restrict__ gpw_w, const float* __restrict__ gpw_b,
        const float* __restrict__ bn1g, const float* __restrict__ bn1b,
        const float* __restrict__ bn1m, const float* __restrict__ bn1v,
        const float* __restrict__ dsb,
        const float* __restrict__ bn2g, const float* __restrict__ bn2b,
        const float* __restrict__ bn2m, const float* __restrict__ bn2v,
        ushort_t* __restrict__ gpwbf,
        float* __restrict__ a1, float* __restrict__ b1,
        float* __restrict__ a2, float* __restrict__ b2,
        float* __restrict__ pooled) {
    int i = blockIdx.x * 256 + threadIdx.x;
    if (i < MID * MID) gpwbf[i] = f2b(gpw_w[i]);
    if (i < Bn * MID) pooled[i] = 0.f;                // atomic accumulator init
    if (i < OCn) {
        float inv = bn2g[i] / sqrtf(bn2v[i] + EPSf);
        a2[i] = inv;
        b2[i] = bn2b[i] + (dsb[i] - bn2m[i]) * inv;   // folds ds bias + BN2
    }
    if (i < MID) {
        float inv = bn1g[i] / sqrtf(bn1v[i] + EPSf);
        a1[i] = inv;
        b1[i] = bn1b[i] + (gpw_b[i] - bn1m[i]) * inv; // folds 1x1 bias + BN1
    }
}

// ------------------------- k_wds -------------------------------------------
// LINEAR layout: wds2[kt][oc][kk], kt = khw*4+icc, kk = channel within icc.
// (k_ds reads A fragments directly from global; no LDS staging, no swizzle.)
__global__ __launch_bounds__(256) void k_wds(const float* __restrict__ dsw,
                                             ushort_t* __restrict__ wds2) {
    int d = blockIdx.x * 256 + threadIdx.x;        // < 36*512*64 = 1179648
    int kk = d & 63, oc = (d >> 6) & 511, kt = d >> 15;
    int khw = kt >> 2, icc = kt & 3;
    int ic = icc * 64 + kk;
    wds2[d] = f2b(dsw[((size_t)oc * CHN + ic) * 9 + khw]);
}

// ------------------------- k_kgen ------------------------------------------
// NOTE: output layout is tap-major: kgen[b][tp*128 + c]  (consumed by k_dw)
__global__ __launch_bounds__(256) void k_kgen(const float* __restrict__ pooled,
                                              const float* __restrict__ wkg,
                                              float* __restrict__ kgen) {
    int idx = blockIdx.x * 256 + threadIdx.x;          // < 16*1152
    int b = idx / 1152, j = idx % 1152;
    int c = j & 127, tp = j >> 7;                      // j = tp*128 + c
    const float* pr = pooled + b * MID;                // channel SUMS (not mean)
    const float* wr = wkg + (size_t)(c * 9 + tp) * MID;
    float s = 0.f;
#pragma unroll 8
    for (int i = 0; i < MID; i++) s += pr[i] * wr[i];
    kgen[idx] = fmaxf(s * (1.f / HW), 0.f);
}

// ------------------------- k_xt --------------------------------------------
// x[b][ch][h][w] fp32 -> xT[b][h][w][ch] bf16, one block per (b,h) row.
// Fused: channel sums of the local half -> atomicAdd pooled[b][c].
__global__ __launch_bounds__(256) void k_xt(const float* __restrict__ x,
                                            ushort_t* __restrict__ xT,
                                            float* __restrict__ pooled) {
    __shared__ ushort_t tile[Wn * 264];  // [w][ch], pad 264 breaks conflicts
    int t = threadIdx.x;
    int bh = blockIdx.x;
    int b = bh / Hh, h = bh % Hh;
    const float* xp = x + ((size_t)b * CHN * Hh + h) * Wn; // + ch*HW + w
    for (int idx = t; idx < CHN * 28; idx += 256) {    // float4 over w
        int ch = idx / 28, q = idx % 28;
        float4 v = *(const float4*)(xp + (size_t)ch * HW + q * 4);
        int w = q * 4;
        tile[w * 264 + ch]       = f2b(v.x);
        tile[(w + 1) * 264 + ch] = f2b(v.y);
        tile[(w + 2) * 264 + ch] = f2b(v.z);
        tile[(w + 3) * 264 + ch] = f2b(v.w);
    }
    __syncthreads();
    int4* dst = (int4*)(xT + (size_t)bh * Wn * CHN);   // contiguous slab
    for (int q = t; q < Wn * CHN / 8; q += 256) {
        int w = q >> 5, c0 = (q & 31) << 3;
        dst[q] = *(const int4*)(tile + w * 264 + c0);
    }
    if (t < MID) {                                     // pool local half
        float s = 0.f;
        for (int w = 0; w < Wn; w++) s += b2f(tile[w * 264 + t]);
        atomicAdd(&pooled[b * MID + t], s);
    }
}

// ------------------------- dw stencil helper --------------------------------
template <int DIL>
DEVI void dw_accum_row(const ushort_t* __restrict__ rp,
                       const float* __restrict__ wtab, int tb,
                       int c0, int wbase, float (&acc)[7][8]) {
    constexpr int NC = 7 + 2 * DIL;
    float wk[3][8];
#pragma unroll
    for (int dw = 0; dw < 3; dw++) {
        float4 lo = *(const float4*)&wtab[(tb + dw) * 128 + c0];
        float4 hi = *(const float4*)&wtab[(tb + dw) * 128 + c0 + 4];
        wk[dw][0] = lo.x; wk[dw][1] = lo.y; wk[dw][2] = lo.z; wk[dw][3] = lo.w;
        wk[dw][4] = hi.x; wk[dw][5] = hi.y; wk[dw][6] = hi.z; wk[dw][7] = hi.w;
    }
    int4 C[NC];
#pragma unroll
    for (int j = 0; j < NC; j++) {
        int w1 = wbase - DIL + j;
        int4 v = make_int4(0, 0, 0, 0);
        if ((unsigned)w1 < (unsigned)Wn)
            v = *(const int4*)(rp + (size_t)w1 * CHN);
        C[j] = v;
    }
#pragma unroll
    for (int j = 0; j < NC; j++) {
        float f[8];
        {
            unsigned u;
            u = (unsigned)C[j].x;
            f[0] = __uint_as_float(u << 16); f[1] = __uint_as_float(u & 0xffff0000u);
            u = (unsigned)C[j].y;
            f[2] = __uint_as_float(u << 16); f[3] = __uint_as_float(u & 0xffff0000u);
            u = (unsigned)C[j].z;
            f[4] = __uint_as_float(u << 16); f[5] = __uint_as_float(u & 0xffff0000u);
            u = (unsigned)C[j].w;
            f[6] = __uint_as_float(u << 16); f[7] = __uint_as_float(u & 0xffff0000u);
        }
#pragma unroll
        for (int dw = 0; dw < 3; dw++) {
            int i = j - dw * DIL;                       // compile-time per (j,dw)
            if (i >= 0 && i <= 6) {
#pragma unroll
                for (int k = 0; k < 8; k++) acc[i][k] += wk[dw][k] * f[k];
            }
        }
    }
}

// ------------------------- k_dw (both stencils) -----------------------------
__global__ __launch_bounds__(256, 3) void k_dw(
        const ushort_t* __restrict__ xT, const float* __restrict__ kgen,
        const float* __restrict__ gdw_w, const float* __restrict__ gdw_b,
        ushort_t* __restrict__ comb) {
    __shared__ float wtab[1152];          // [tap][128ch]
    int t = threadIdx.x;
    int h = blockIdx.x, by = blockIdx.y;
    int b = by >> 1, br = by & 1;
    if (br == 0) {                        // kgen already tap-major
        const float4* src = (const float4*)(kgen + (size_t)b * 1152);
        float4* dstw = (float4*)wtab;
        dstw[t] = src[t];
        if (t < 32) dstw[256 + t] = src[256 + t];      // 288 float4 total
    } else {                              // transpose gdw_w [c][9] -> [tap][c]
        for (int e4 = t; e4 < 288; e4 += 256) {
            float4 v = *(const float4*)(gdw_w + (size_t)e4 * 4);
            int e = e4 * 4;
            wtab[(e % 9) * 128 + e / 9]             = v.x;
            wtab[((e + 1) % 9) * 128 + (e + 1) / 9] = v.y;
            wtab[((e + 2) % 9) * 128 + (e + 2) / 9] = v.z;
            wtab[((e + 3) % 9) * 128 + (e + 3) / 9] = v.w;
        }
    }
    __syncthreads();
    int cg = t & 15, wl = t >> 4, c0 = cg << 3, wbase = 7 * wl;
    const ushort_t* xb = xT + (size_t)b * HW * CHN + (br ? MID : 0) + c0;
    float acc[7][8];
    if (br == 0) {
#pragma unroll
        for (int i = 0; i < 7; i++)
#pragma unroll
            for (int k = 0; k < 8; k++) acc[i][k] = 0.f;
#pragma unroll
        for (int dh = -1; dh <= 1; dh++) {
            int h1 = h + dh;
            if ((unsigned)h1 < (unsigned)Hh)
                dw_accum_row<1>(xb + (size_t)h1 * Wn * CHN, wtab,
                                (dh + 1) * 3, c0, wbase, acc);
        }
    } else {
        float4 b0 = *(const float4*)(gdw_b + c0);
        float4 b4 = *(const float4*)(gdw_b + c0 + 4);
#pragma unroll
        for (int i = 0; i < 7; i++) {
            acc[i][0] = b0.x; acc[i][1] = b0.y; acc[i][2] = b0.z; acc[i][3] = b0.w;
            acc[i][4] = b4.x; acc[i][5] = b4.y; acc[i][6] = b4.z; acc[i][7] = b4.w;
        }
#pragma unroll
        for (int dh = -1; dh <= 1; dh++) {
            int h1 = h + 2 * dh;
            if ((unsigned)h1 < (unsigned)Hh)
                dw_accum_row<2>(xb + (size_t)h1 * Wn * CHN, wtab,
                                (dh + 1) * 3, c0, wbase, acc);
        }
    }
    int gch = (br ? MID : 0) + c0;
    int icc = gch >> 6, cch = (gch & 63) >> 3;
#pragma unroll
    for (int i = 0; i < 7; i++) {
        int w = wbase + i;
        int4 O;
        O.x = pack2(acc[i][0], acc[i][1]);
        O.y = pack2(acc[i][2], acc[i][3]);
        O.z = pack2(acc[i][4], acc[i][5]);
        O.w = pack2(acc[i][6], acc[i][7]);
        int w2 = w >> 1, p = w & 1, ph = cch ^ (w2 & 7);
        *(int4*)(comb + (size_t)b * C_B + (size_t)h * C_H + p * C_P
                 + icc * C_I + w2 * 64 + ph * 8) = O;
    }
}

// ------------------------- k_pw (1x1 MFMA + BN1 + ReLU, in place) -----------
__global__ __launch_bounds__(256, 3) void k_pw(
        ushort_t* __restrict__ comb, const ushort_t* __restrict__ gpwbf,
        const float* __restrict__ a1, const float* __restrict__ b1) {
    __shared__ ushort_t pbuf[112 * 136];  // P image (28KB) / EP overlay (30.5KB)
    int t = threadIdx.x, lane = t & 63, wave = t >> 6;
    int h = blockIdx.x, b = blockIdx.y;
    const char* base = (const char*)(comb + (size_t)b * C_B + (size_t)h * C_H);
    // stage: slab s = p*2 + (icc-2); LDS image [s][w2 56][64ch], 3584 ush/slab
    for (int j = wave; j < 28; j += 4) {
        int s = j / 7, cc = j - s * 7;
        int p = s >> 1, ic = 2 + (s & 1);
        const char* src = base + ((size_t)p * C_P + (size_t)ic * C_I) * 2
                          + cc * 1024 + lane * 16;
        gl_lds16(src, (char*)pbuf + (size_t)s * 7168 + cc * 1024);
    }
    __syncthreads();
    // --- MFMA: px row = p*56 + w2 ... mapped row = m*16+mrow; w2&7 == mrow&7
    int mrow = lane & 15, quad = lane >> 4;
    const short* gw = (const short*)gpwbf;
    f32x4 acc2[7][2] = {};
#pragma unroll
    for (int ks = 0; ks < 4; ks++) {
        bf16x8 bfr[2];
#pragma unroll
        for (int n = 0; n < 2; n++)
            bfr[n] = *(const bf16x8*)(gw + (size_t)(wave * 32 + n * 16 + mrow) * MID
                                         + ks * 32 + quad * 8);
        int kq = ks * 4 + quad;                        // chunk index 0..15
#pragma unroll
        for (int m = 0; m < 7; m++) {
            int row = m * 16 + mrow;                   // px = p*56 + w2
            int p = (row >= 56) ? 1 : 0;
            int w2 = row - 56 * p;
            int slab = p * 2 + (kq >> 3);
            int ph = (kq & 7) ^ (w2 & 7);
            bf16x8 af = *(const bf16x8*)(pbuf + (size_t)slab * 3584
                                         + w2 * 64 + ph * 8);
#pragma unroll
            for (int n = 0; n < 2; n++)
                acc2[m][n] = __builtin_amdgcn_mfma_f32_16x16x32_bf16(
                    af, bfr[n], acc2[m][n], 0, 0, 0);
        }
    }
    __syncthreads();                     // all waves done reading P -> EP overlay
#pragma unroll
    for (int m = 0; m < 7; m++)
#pragma unroll
        for (int n = 0; n < 2; n++) {
            int oc2 = wave * 32 + n * 16 + mrow;        // D col = lane&15
            float al = a1[oc2], be = b1[oc2];
#pragma unroll
            for (int r = 0; r < 4; r++) {               // D row = quad*4+reg
                int px = m * 16 + quad * 4 + r;         // px row id
                pbuf[px * 136 + oc2] = f2b(fmaxf(acc2[m][n][r] * al + be, 0.f));
            }
        }
    __syncthreads();                     // EP complete
    int cg = t & 15, wl = t >> 4, c0 = cg << 3;
    for (int ws = 0; ws < 7; ws++) {     // 16B stores, comb-swizzled, in place
        int row = ws * 16 + wl;          // row = p*56 + w2 ordering of MFMA M
        int p = (row >= 56) ? 1 : 0;
        int w2 = row - 56 * p;
        int4 v = *(const int4*)(pbuf + (size_t)row * 136 + c0);
        int gch = MID + c0;
        int icc = gch >> 6, cch = (gch & 63) >> 3, ph = cch ^ (w2 & 7);
        *(int4*)(comb + (size_t)b * C_B + (size_t)h * C_H + (size_t)p * C_P
                 + icc * C_I + w2 * 64 + ph * 8) = v;
    }
}

// ------------------------- k_ds --------------------------------------------
// R11: ring-3 B buffers staged 2 ahead; EXACTLY 4 gl_lds/wave/tile (dummies ->
// ldummy, source wds2).  zh0 blocks: prologue zeroes half-0 of all 3 buffers;
// kh==0 tiles never DMA half-0 (dummy slots), so the zeros persist through
// kt=0..11; kh>=1 tiles re-fill half-0 with real data.  A reg-prefetched 1
// ahead.  Loop sync: raw s_barrier + counted vmcnt(12), never 0 in the loop.
__global__ __launch_bounds__(256, 2) void k_ds(
        const ushort_t* __restrict__ comb, const ushort_t* __restrict__ wds2,
        const float* __restrict__ a2, const float* __restrict__ b2,
        float* __restrict__ out) {
    __shared__ __align__(16) ushort_t lB[3][128 * 64]; // 3 x 16 KB, swizzled
    __shared__ __align__(16) ushort_t ldummy[512];     // 1 KB dummy-DMA target
    int t = threadIdx.x, lane = t & 63, wave = t >> 6;
    // XCD-aware decode: 4 oc-tiles of one (b,oh-pair) -> same XCD, contiguous
    int g = blockIdx.x;
    int xcd = g & 7, s = g >> 3;        // s in [0,224)
    int octile = s & 3, pl = s >> 2;    // pl in [0,56)
    int pair = xcd * 56 + pl;           // [0,448)
    int bb = pair / 28, ohp = pair % 28;
    int oh0 = ohp * 2, oc0 = octile * 128;
    int mrow = lane & 15, quad = lane >> 4;
    int wm = wave & 1, wn = wave >> 1;

    // per-thread A base: row = oc0 + wm*64 + m*16 + mrow, kk = ks*32 + quad*8
    const ushort_t* Abase = wds2 + (size_t)(oc0 + wm * 64 + mrow) * 64 + quad * 8;

    // --- B stage: EXACTLY 4 gl_lds per wave per tile (static vmem count).
    //     zh0 tiles: osub==0 slots become dummies (half-0 stays prologue-zero).
    auto STAGE_B = [&](int ktn, ushort_t* Bb) {
        int khw = ktn >> 2, icc = ktn & 3;
        int kh = khw / 3, kw = khw - kh * 3;
        int p = (kw == 1) ? 0 : 1;
        bool zh0 = (oh0 == 0) && (kh == 0);        // r=-1 rows must stay zero
        int ldsShift = (kw == 0) ? 128 : 0;        // row0 holds w2=-1 zeros
        if (kw == 0 && t < 16) {                   // zero w2=-1 row, both halves
            int4 z = {0, 0, 0, 0};
            *(int4*)(Bb + (t >> 3) * 4096 + (t & 7) * 8) = z;
        }
#pragma unroll
        for (int i = 0; i < 4; i++) {
            int j = wave + 4 * i;                  // 0..15
            bool real = (j < 14) && !(zh0 && j < 7);
            if (real) {
                int osub = (j >= 7) ? 1 : 0, jj = j - osub * 7;
                int r = 2 * oh0 + 2 * osub + kh - 1;   // 0..111 here
                const char* bsrc = (const char*)comb
                    + ((size_t)bb * C_B + (size_t)r * C_H + (size_t)p * C_P
                       + (size_t)icc * C_I) * 2 + jj * 1024 + lane * 16;
                gl_lds16(bsrc, (char*)Bb + osub * 8192 + ldsShift + jj * 1024);
            } else {
                // dummy: keeps per-wave vmem count uniform; never read
                gl_lds16((const char*)wds2 + lane * 16, (char*)ldummy);
            }
        }
    };

    f32x4 acc[4][4] = {};
    bf16x8 afA[2][4], afB[2][4];

    // --- prologue ---
    if (oh0 == 0) {                      // zero half-0 of all 3 ring buffers
        int4 z = {0, 0, 0, 0};
#pragma unroll
        for (int r3 = 0; r3 < 3; r3++) {
            *(int4*)((ushort_t*)lB[r3] + t * 8) = z;          // bytes [0,4096)
            *(int4*)((ushort_t*)lB[r3] + 2048 + t * 8) = z;   // [4096,8192)
        }
    }
    STAGE_B(0, (ushort_t*)lB[0]);
    STAGE_B(1, (ushort_t*)lB[1]);
    {
        const ushort_t* A0 = Abase;
#pragma unroll
        for (int ks = 0; ks < 2; ks++)
#pragma unroll
            for (int m = 0; m < 4; m++)
                afA[ks][m] = *(const bf16x8*)(A0 + m * 1024 + ks * 32);
    }
    asm volatile("s_waitcnt vmcnt(0) lgkmcnt(0)" ::: "memory");
    __builtin_amdgcn_s_barrier();

    // --- one pipelined iteration (compute kt; prefetch A(kt+1), B(kt+2)) ---
    auto ITER = [&](int kt, bf16x8 (&afC)[2][4], bf16x8 (&afN)[2][4]) {
        const ushort_t* An = Abase + (size_t)(kt + 1) * 32768;
#pragma unroll
        for (int ks = 0; ks < 2; ks++)
#pragma unroll
            for (int m = 0; m < 4; m++)
                afN[ks][m] = *(const bf16x8*)(An + m * 1024 + ks * 32);
        int ktn = (kt + 2 > 35) ? 35 : (kt + 2);   // kt=34: benign re-stage
        STAGE_B(ktn, (ushort_t*)lB[(kt + 2) % 3]);
        // compute tile kt from lB[kt%3]
        const ushort_t* Bb = (const ushort_t*)lB[kt % 3];
        int khw = kt >> 2, kh = khw / 3, kw = khw - kh * 3;
        int bk = (mrow + ((kw == 0) ? 7 : 0)) & 7; // B swizzle key
#pragma unroll
        for (int ks = 0; ks < 2; ks++) {
            bf16x8 bfv[4];
#pragma unroll
            for (int n = 0; n < 4; n++) {
                int nr = wn * 64 + n * 16 + mrow;
                int ph = (ks * 4 + quad) ^ bk;
                bfv[n] = *(const bf16x8*)(Bb + nr * 64 + ph * 8);
            }
#pragma unroll
            for (int m = 0; m < 4; m++)
#pragma unroll
                for (int n = 0; n < 4; n++)
                    acc[m][n] = __builtin_amdgcn_mfma_f32_16x16x32_bf16(
                        afC[ks][m], bfv[n], acc[m][n], 0, 0, 0);
        }
        // counted pre-barrier wait: leave this iter's 8 A + 4 B in flight;
        // everything older (incl. all waves' B(kt+1) DMA) is complete.
        asm volatile("s_waitcnt vmcnt(12)" ::: "memory");
        asm volatile("s_waitcnt lgkmcnt(0)" ::: "memory");
        __builtin_amdgcn_s_barrier();
    };

    for (int kt = 0; kt < 34; kt += 2) {
        ITER(kt, afA, afB);
        ITER(kt + 1, afB, afA);
    }
    ITER(34, afA, afB);
    {   // peeled kt=35: compute only (compiler emits its own counted vmcnt)
        const ushort_t* Bb = (const ushort_t*)lB[35 % 3];
        int bk = (mrow + 0) & 7;                   // kt=35: khw=8, kw=2
#pragma unroll
        for (int ks = 0; ks < 2; ks++) {
            bf16x8 bfv[4];
#pragma unroll
            for (int n = 0; n < 4; n++) {
                int nr = wn * 64 + n * 16 + mrow;
                int ph = (ks * 4 + quad) ^ bk;
                bfv[n] = *(const bf16x8*)(Bb + nr * 64 + ph * 8);
            }
#pragma unroll
            for (int m = 0; m < 4; m++)
#pragma unroll
                for (int n = 0; n < 4; n++)
                    acc[m][n] = __builtin_amdgcn_mfma_f32_16x16x32_bf16(
                        afB[ks][m], bfv[n], acc[m][n], 0, 0, 0);
        }
    }
    // --- epilogue: BN2 + ReLU; D row=oc (quad*4+r), col=n (mrow) ---
#pragma unroll
    for (int m = 0; m < 4; m++) {
#pragma unroll
        for (int r4 = 0; r4 < 4; r4++) {
            int oc = oc0 + wm * 64 + m * 16 + quad * 4 + r4;
            float al = a2[oc], be = b2[oc];
#pragma unroll
            for (int n = 0; n < 4; n++) {
                int nr = wn * 64 + n * 16 + mrow;
                int osub = nr >> 6, ow = nr & 63;
                if (ow < OWn) {
                    float v = fmaxf(acc[m][n][r4] * al + be, 0.f);
                    out[((size_t)(bb * OCn + oc) * OHn + (oh0 + osub)) * OWn + ow] = v;
                }
            }
        }
    }
}

// ------------------------- launch ------------------------------------------
extern "C" void kernel_launch(void* const* d_in, const int* in_sizes, int n_in,
                              void* d_out, int out_size, void* d_ws, size_t ws_size,
                              hipStream_t stream) {
    const float* x     = (const float*)d_in[0];
    const float* wkg   = (const float*)d_in[1];
    const float* gdw_w = (const float*)d_in[2];
    const float* gdw_b = (const float*)d_in[3];
    const float* gpw_w = (const float*)d_in[4];
    const float* gpw_b = (const float*)d_in[5];
    const float* bn1g  = (const float*)d_in[6];
    const float* bn1b  = (const float*)d_in[7];
    const float* bn1m  = (const float*)d_in[8];
    const float* bn1v  = (const float*)d_in[9];
    const float* dsw   = (const float*)d_in[10];
    const float* dsb   = (const float*)d_in[11];
    const float* bn2g  = (const float*)d_in[12];
    const float* bn2b  = (const float*)d_in[13];
    const float* bn2m  = (const float*)d_in[14];
    const float* bn2v  = (const float*)d_in[15];

    // workspace layout (bytes). PROVEN footprint — do not add slots.
    char* ws = (char*)d_ws;
    float*    pooled = (float*)(ws + 0);           //  2048 f32 (sums)
    float*    kgen   = (float*)(ws + 8192);        // 18432 f32 (tap-major)
    float*    a1     = (float*)(ws + 81920);       //  128 f32
    float*    b1     = (float*)(ws + 82432);
    float*    a2     = (float*)(ws + 82944);       //  512 f32
    float*    b2     = (float*)(ws + 84992);
    ushort_t* gpwbf  = (ushort_t*)(ws + 87040);    // 16384 bf16 [87040,119808)
    ushort_t* wds2   = (ushort_t*)(ws + 119808);   // 36*512*64 bf16 (2.36 MB)
    ushort_t* comb   = (ushort_t*)(ws + 2479104);  // 102,760,448 B
    // xT (NHWC bf16 copy of x) lives in d_out: exactly 102,760,448 B, consumed
    // by k_dw before k_ds overwrites d_out with the real output.
    ushort_t* xT  = (ushort_t*)d_out;
    float*    out = (float*)d_out;

    k_prep<<<64, 256, 0, stream>>>(gpw_w, gpw_b, bn1g, bn1b, bn1m, bn1v,
                                   dsb, bn2g, bn2b, bn2m, bn2v,
                                   gpwbf, a1, b1, a2, b2, pooled);
    k_wds <<<4608, 256, 0, stream>>>(dsw, wds2);
    k_xt  <<<1792, 256, 0, stream>>>(x, xT, pooled);
    k_kgen<<<72, 256, 0, stream>>>(pooled, wkg, kgen);
    k_dw  <<<dim3(Hh, Bn * 2), 256, 0, stream>>>(xT, kgen, gdw_w, gdw_b, comb);
    k_pw  <<<dim3(Hh, Bn), 256, 0, stream>>>(comb, gpwbf, a1, b1);
    k_ds  <<<1792, 256, 0, stream>>>(comb, wds2, a2, b2, out);
}

// Round 10
// 338.125 us; speedup vs baseline: 1.5044x; 1.5044x over previous
//
#include <hip/hip_runtime.h>

// ---------------------------------------------------------------------------
// LocalGlobalBlock on MI355X.  (R12: revert k_ds to proven R7 2-barrier DMA
// structure — A-direct + counted-vmcnt variants (R8-R11) measured 2x slower.
// k_prep folded into k_wds to save one launch.)
//   k_wds  : [merged prep] BN folds, gpw->bf16, pooled zero  +  ds_w -> wds2
//            bf16 [khw*4+icc][oc][64ch], 16B chunks XOR-swizzled
//   k_xt   : x NCHW fp32 -> xT NHWC bf16 (in d_out; exact fit) + fused pool
//   k_kgen : relu((pooled_sum/HW) @ W_kg^T) -> kgen[16][9][128]  (tap-major)
//   k_dw   : BOTH depthwise stencils (br=0 local dil1, br=1 global dil2),
//            LDS = wtab only (4.6KB).  br=0 -> comb ch0..127 final;
//            br=1 -> comb ch128..255 holds P (pre-1x1) bits.
//   k_pw   : per (b,h): DMA P slabs comb->LDS, 1x1 MFMA + BN1 + ReLU,
//            overwrite same comb slots in place.
//   k_ds   : downsample 3x3 s2 implicit GEMM, 128oc x 128n, BK=64, 36 steps,
//            global_load_lds(16B) staging for A AND B, XOR-swizzled LDS,
//            2 barriers/step, XCD-aware decode.  (Proven: 170us, MfmaUtil 34%)
//
// comb layout: [b][h][p][icc4][w2 56][64ch], w = 2*w2+p; chunk c (16B=8ch)
// stored at position c^(w2&7) -> DMA deposits a conflict-free LDS image.
// ---------------------------------------------------------------------------

#define DEVI static __device__ __forceinline__

using bf16x8 = __attribute__((ext_vector_type(8))) short;  // 8 bf16 (4 VGPRs)
using f32x4  = __attribute__((ext_vector_type(4))) float;  // MFMA accumulator
typedef unsigned short ushort_t;

constexpr int Bn = 16, MID = 128, CHN = 256, Hh = 112, Wn = 112;
constexpr int OHn = 56, OWn = 56, OCn = 512;
constexpr int HW  = Hh * Wn;        // 12544
constexpr float EPSf = 1e-5f;

// comb strides in ushorts
constexpr size_t C_I = 56 * 64;          // 3584  (per icc)
constexpr size_t C_P = 4 * C_I;          // 14336 (per parity)
constexpr size_t C_H = 2 * C_P;          // 28672 (per h row)
constexpr size_t C_B = (size_t)Hh * C_H; // 3211264 (per batch)

DEVI ushort_t f2b(float f) {  // fp32 -> bf16 RNE (finite data only)
    unsigned u = __float_as_uint(f);
    return (ushort_t)((u + 0x7FFFu + ((u >> 16) & 1u)) >> 16);
}
DEVI float b2f(ushort_t s) { return __uint_as_float(((unsigned)s) << 16); }
DEVI int pack2(float a, float b) {
    return (int)f2b(a) | ((int)f2b(b) << 16);
}

DEVI void gl_lds16(const void* g, void* l) {   // async global->LDS, 16B/lane
    __builtin_amdgcn_global_load_lds(
        (const __attribute__((address_space(1))) unsigned int*)g,
        (__attribute__((address_space(3))) unsigned int*)l, 16, 0, 0);
}

// ------------------------- k_wds (+ merged prep) ----------------------------
// wds2[kb][oc][64], kb = khw*4+icc; chunk ph holds logical chunk ph^(oc&7).
// Blocks 0..63 additionally perform the one-time prep (guarded by index).
__global__ __launch_bounds__(256) void k_wds(
        const float* __restrict__ dsw, ushort_t* __restrict__ wds2,
        const float* __restrict__ gpw_w, const float* __restrict__ gpw_b,
        const float* __restrict__ bn1g, const float* __restrict__ bn1b,
        const float* __restrict__ bn1m, const float* __restrict__ bn1v,
        const float* __restrict__ dsb,
        const float* __restrict__ bn2g, const float* __restrict__ bn2b,
        const float* __restrict__ bn2m, const float* __restrict__ bn2v,
        ushort_t* __restrict__ gpwbf,
        float* __restrict__ a1, float* __restrict__ b1,
        float* __restrict__ a2, float* __restrict__ b2,
        float* __restrict__ pooled) {
    int d = blockIdx.x * 256 + threadIdx.x;        // < 36*512*64 = 1179648
    int j = d & 63, oc = (d >> 6) & 511, kb = d >> 15;
    int khw = kb >> 2, icc = kb & 3;
    int ph = j >> 3, c = ph ^ (oc & 7);
    int ic = icc * 64 + c * 8 + (j & 7);
    wds2[d] = f2b(dsw[((size_t)oc * CHN + ic) * 9 + khw]);
    // ---- merged k_prep (one-time scalars; i == d) ----
    int i = d;
    if (i < MID * MID) gpwbf[i] = f2b(gpw_w[i]);
    if (i < Bn * MID) pooled[i] = 0.f;                // atomic accumulator init
    if (i < OCn) {
        float inv = bn2g[i] / sqrtf(bn2v[i] + EPSf);
        a2[i] = inv;
        b2[i] = bn2b[i] + (dsb[i] - bn2m[i]) * inv;   // folds ds bias + BN2
    }
    if (i < MID) {
        float inv = bn1g[i] / sqrtf(bn1v[i] + EPSf);
        a1[i] = inv;
        b1[i] = bn1b[i] + (gpw_b[i] - bn1m[i]) * inv; // folds 1x1 bias + BN1
    }
}

// ------------------------- k_kgen ------------------------------------------
// NOTE: output layout is tap-major: kgen[b][tp*128 + c]  (consumed by k_dw)
__global__ __launch_bounds__(256) void k_kgen(const float* __restrict__ pooled,
                                              const float* __restrict__ wkg,
                                              float* __restrict__ kgen) {
    int idx = blockIdx.x * 256 + threadIdx.x;          // < 16*1152
    int b = idx / 1152, j = idx % 1152;
    int c = j & 127, tp = j >> 7;                      // j = tp*128 + c
    const float* pr = pooled + b * MID;                // channel SUMS (not mean)
    const float* wr = wkg + (size_t)(c * 9 + tp) * MID;
    float s = 0.f;
#pragma unroll 8
    for (int i = 0; i < MID; i++) s += pr[i] * wr[i];
    kgen[idx] = fmaxf(s * (1.f / HW), 0.f);
}

// ------------------------- k_xt --------------------------------------------
// x[b][ch][h][w] fp32 -> xT[b][h][w][ch] bf16, one block per (b,h) row.
// Fused: channel sums of the local half -> atomicAdd pooled[b][c].
__global__ __launch_bounds__(256) void k_xt(const float* __restrict__ x,
                                            ushort_t* __restrict__ xT,
                                            float* __restrict__ pooled) {
    __shared__ ushort_t tile[Wn * 264];  // [w][ch], pad 264 breaks conflicts
    int t = threadIdx.x;
    int bh = blockIdx.x;
    int b = bh / Hh, h = bh % Hh;
    const float* xp = x + ((size_t)b * CHN * Hh + h) * Wn; // + ch*HW + w
    for (int idx = t; idx < CHN * 28; idx += 256) {    // float4 over w
        int ch = idx / 28, q = idx % 28;
        float4 v = *(const float4*)(xp + (size_t)ch * HW + q * 4);
        int w = q * 4;
        tile[w * 264 + ch]       = f2b(v.x);
        tile[(w + 1) * 264 + ch] = f2b(v.y);
        tile[(w + 2) * 264 + ch] = f2b(v.z);
        tile[(w + 3) * 264 + ch] = f2b(v.w);
    }
    __syncthreads();
    int4* dst = (int4*)(xT + (size_t)bh * Wn * CHN);   // contiguous slab
    for (int q = t; q < Wn * CHN / 8; q += 256) {
        int w = q >> 5, c0 = (q & 31) << 3;
        dst[q] = *(const int4*)(tile + w * 264 + c0);
    }
    if (t < MID) {                                     // pool local half
        float s = 0.f;
        for (int w = 0; w < Wn; w++) s += b2f(tile[w * 264 + t]);
        atomicAdd(&pooled[b * MID + t], s);
    }
}

// ------------------------- dw stencil helper --------------------------------
// One tap row: loads NC=7+2*DIL contiguous 16B chunks (w1 = wbase-DIL+j),
// converts each chunk to f32 once, applies to the <=3 accumulators that use
// it.  Accumulation order per output (dw ascending) is bit-stable.
// wtab layout: [tap][128ch].
template <int DIL>
DEVI void dw_accum_row(const ushort_t* __restrict__ rp,
                       const float* __restrict__ wtab, int tb,
                       int c0, int wbase, float (&acc)[7][8]) {
    constexpr int NC = 7 + 2 * DIL;
    float wk[3][8];
#pragma unroll
    for (int dw = 0; dw < 3; dw++) {
        float4 lo = *(const float4*)&wtab[(tb + dw) * 128 + c0];
        float4 hi = *(const float4*)&wtab[(tb + dw) * 128 + c0 + 4];
        wk[dw][0] = lo.x; wk[dw][1] = lo.y; wk[dw][2] = lo.z; wk[dw][3] = lo.w;
        wk[dw][4] = hi.x; wk[dw][5] = hi.y; wk[dw][6] = hi.z; wk[dw][7] = hi.w;
    }
    int4 C[NC];
#pragma unroll
    for (int j = 0; j < NC; j++) {
        int w1 = wbase - DIL + j;
        int4 v = make_int4(0, 0, 0, 0);
        if ((unsigned)w1 < (unsigned)Wn)
            v = *(const int4*)(rp + (size_t)w1 * CHN);
        C[j] = v;
    }
#pragma unroll
    for (int j = 0; j < NC; j++) {
        float f[8];
        {
            unsigned u;
            u = (unsigned)C[j].x;
            f[0] = __uint_as_float(u << 16); f[1] = __uint_as_float(u & 0xffff0000u);
            u = (unsigned)C[j].y;
            f[2] = __uint_as_float(u << 16); f[3] = __uint_as_float(u & 0xffff0000u);
            u = (unsigned)C[j].z;
            f[4] = __uint_as_float(u << 16); f[5] = __uint_as_float(u & 0xffff0000u);
            u = (unsigned)C[j].w;
            f[6] = __uint_as_float(u << 16); f[7] = __uint_as_float(u & 0xffff0000u);
        }
#pragma unroll
        for (int dw = 0; dw < 3; dw++) {
            int i = j - dw * DIL;                       // compile-time per (j,dw)
            if (i >= 0 && i <= 6) {
#pragma unroll
                for (int k = 0; k < 8; k++) acc[i][k] += wk[dw][k] * f[k];
            }
        }
    }
}

// ------------------------- k_dw (both stencils) -----------------------------
// Block = (h, b*2+br). 256 threads = 16 cgrps x 16 wl; thread owns 7 consec w.
// br=0: local dw (kernels from kgen) -> comb ch0..127 (final values)
// br=1: global dilated dw (gdw) -> comb ch128..255 (P bits, pre-1x1)
// LDS = wtab only (4.6KB) -> high occupancy, no post-load barriers.
__global__ __launch_bounds__(256, 3) void k_dw(
        const ushort_t* __restrict__ xT, const float* __restrict__ kgen,
        const float* __restrict__ gdw_w, const float* __restrict__ gdw_b,
        ushort_t* __restrict__ comb) {
    __shared__ float wtab[1152];          // [tap][128ch]
    int t = threadIdx.x;
    int h = blockIdx.x, by = blockIdx.y;
    int b = by >> 1, br = by & 1;
    if (br == 0) {                        // kgen already tap-major
        const float4* src = (const float4*)(kgen + (size_t)b * 1152);
        float4* dstw = (float4*)wtab;
        dstw[t] = src[t];
        if (t < 32) dstw[256 + t] = src[256 + t];      // 288 float4 total
    } else {                              // transpose gdw_w [c][9] -> [tap][c]
        for (int e4 = t; e4 < 288; e4 += 256) {
            float4 v = *(const float4*)(gdw_w + (size_t)e4 * 4);
            int e = e4 * 4;
            wtab[(e % 9) * 128 + e / 9]             = v.x;
            wtab[((e + 1) % 9) * 128 + (e + 1) / 9] = v.y;
            wtab[((e + 2) % 9) * 128 + (e + 2) / 9] = v.z;
            wtab[((e + 3) % 9) * 128 + (e + 3) / 9] = v.w;
        }
    }
    __syncthreads();
    int cg = t & 15, wl = t >> 4, c0 = cg << 3, wbase = 7 * wl;
    const ushort_t* xb = xT + (size_t)b * HW * CHN + (br ? MID : 0) + c0;
    float acc[7][8];
    if (br == 0) {
#pragma unroll
        for (int i = 0; i < 7; i++)
#pragma unroll
            for (int k = 0; k < 8; k++) acc[i][k] = 0.f;
#pragma unroll
        for (int dh = -1; dh <= 1; dh++) {
            int h1 = h + dh;
            if ((unsigned)h1 < (unsigned)Hh)
                dw_accum_row<1>(xb + (size_t)h1 * Wn * CHN, wtab,
                                (dh + 1) * 3, c0, wbase, acc);
        }
    } else {
        float4 b0 = *(const float4*)(gdw_b + c0);
        float4 b4 = *(const float4*)(gdw_b + c0 + 4);
#pragma unroll
        for (int i = 0; i < 7; i++) {
            acc[i][0] = b0.x; acc[i][1] = b0.y; acc[i][2] = b0.z; acc[i][3] = b0.w;
            acc[i][4] = b4.x; acc[i][5] = b4.y; acc[i][6] = b4.z; acc[i][7] = b4.w;
        }
#pragma unroll
        for (int dh = -1; dh <= 1; dh++) {
            int h1 = h + 2 * dh;
            if ((unsigned)h1 < (unsigned)Hh)
                dw_accum_row<2>(xb + (size_t)h1 * Wn * CHN, wtab,
                                (dh + 1) * 3, c0, wbase, acc);
        }
    }
    int gch = (br ? MID : 0) + c0;
    int icc = gch >> 6, cch = (gch & 63) >> 3;
#pragma unroll
    for (int i = 0; i < 7; i++) {
        int w = wbase + i;
        int4 O;
        O.x = pack2(acc[i][0], acc[i][1]);
        O.y = pack2(acc[i][2], acc[i][3]);
        O.z = pack2(acc[i][4], acc[i][5]);
        O.w = pack2(acc[i][6], acc[i][7]);
        int w2 = w >> 1, p = w & 1, ph = cch ^ (w2 & 7);
        *(int4*)(comb + (size_t)b * C_B + (size_t)h * C_H + p * C_P
                 + icc * C_I + w2 * 64 + ph * 8) = O;
    }
}

// ------------------------- k_pw (1x1 MFMA + BN1 + ReLU, in place) -----------
// Per (b,h): DMA 4 P slabs (p x icc{2,3}, 7KB each) comb->LDS, MFMA
// D[px][oc2] = P[px][:] . gpwbf[oc2][:], EP overlay, overwrite same slots.
__global__ __launch_bounds__(256, 3) void k_pw(
        ushort_t* __restrict__ comb, const ushort_t* __restrict__ gpwbf,
        const float* __restrict__ a1, const float* __restrict__ b1) {
    __shared__ ushort_t pbuf[112 * 136];  // P image (28KB) / EP overlay (30.5KB)
    int t = threadIdx.x, lane = t & 63, wave = t >> 6;
    int h = blockIdx.x, b = blockIdx.y;
    const char* base = (const char*)(comb + (size_t)b * C_B + (size_t)h * C_H);
    // stage: slab s = p*2 + (icc-2); LDS image [s][w2 56][64ch], 3584 ush/slab
    for (int j = wave; j < 28; j += 4) {
        int s = j / 7, cc = j - s * 7;
        int p = s >> 1, ic = 2 + (s & 1);
        const char* src = base + ((size_t)p * C_P + (size_t)ic * C_I) * 2
                          + cc * 1024 + lane * 16;
        gl_lds16(src, (char*)pbuf + (size_t)s * 7168 + cc * 1024);
    }
    __syncthreads();
    // --- MFMA: px row = p*56 + w2 ... mapped row = m*16+mrow; w2&7 == mrow&7
    int mrow = lane & 15, quad = lane >> 4;
    const short* gw = (const short*)gpwbf;
    f32x4 acc2[7][2] = {};
#pragma unroll
    for (int ks = 0; ks < 4; ks++) {
        bf16x8 bfr[2];
#pragma unroll
        for (int n = 0; n < 2; n++)
            bfr[n] = *(const bf16x8*)(gw + (size_t)(wave * 32 + n * 16 + mrow) * MID
                                         + ks * 32 + quad * 8);
        int kq = ks * 4 + quad;                        // chunk index 0..15
#pragma unroll
        for (int m = 0; m < 7; m++) {
            int row = m * 16 + mrow;                   // px = p*56 + w2
            int p = (row >= 56) ? 1 : 0;
            int w2 = row - 56 * p;
            int slab = p * 2 + (kq >> 3);
            int ph = (kq & 7) ^ (w2 & 7);
            bf16x8 af = *(const bf16x8*)(pbuf + (size_t)slab * 3584
                                         + w2 * 64 + ph * 8);
#pragma unroll
            for (int n = 0; n < 2; n++)
                acc2[m][n] = __builtin_amdgcn_mfma_f32_16x16x32_bf16(
                    af, bfr[n], acc2[m][n], 0, 0, 0);
        }
    }
    __syncthreads();                     // all waves done reading P -> EP overlay
#pragma unroll
    for (int m = 0; m < 7; m++)
#pragma unroll
        for (int n = 0; n < 2; n++) {
            int oc2 = wave * 32 + n * 16 + mrow;        // D col = lane&15
            float al = a1[oc2], be = b1[oc2];
#pragma unroll
            for (int r = 0; r < 4; r++) {               // D row = quad*4+reg
                int px = m * 16 + quad * 4 + r;         // px row id
                pbuf[px * 136 + oc2] = f2b(fmaxf(acc2[m][n][r] * al + be, 0.f));
            }
        }
    __syncthreads();                     // EP complete
    int cg = t & 15, wl = t >> 4, c0 = cg << 3;
    for (int ws = 0; ws < 7; ws++) {     // 16B stores, comb-swizzled, in place
        int row = ws * 16 + wl;          // row = p*56 + w2 ordering of MFMA M
        int p = (row >= 56) ? 1 : 0;
        int w2 = row - 56 * p;
        int4 v = *(const int4*)(pbuf + (size_t)row * 136 + c0);
        int gch = MID + c0;
        int icc = gch >> 6, cch = (gch & 63) >> 3, ph = cch ^ (w2 & 7);
        *(int4*)(comb + (size_t)b * C_B + (size_t)h * C_H + (size_t)p * C_P
                 + icc * C_I + w2 * 64 + ph * 8) = v;
    }
}

// ------------------------- k_ds --------------------------------------------
// 128 oc x 128 n (2 oh rows x 56 ow + pad), BK=64, 36 steps x 32 MFMA/wave.
// All staging via global_load_lds(16B); swizzled LDS -> conflict-free reads.
// (Proven R7 structure: 2 barriers/step; A+B both DMA-staged.)
__global__ __launch_bounds__(256) void k_ds(
        const ushort_t* __restrict__ comb, const ushort_t* __restrict__ wds2,
        const float* __restrict__ a2, const float* __restrict__ b2,
        float* __restrict__ out) {
    __shared__ ushort_t lA[128 * 64];   // [oc][64ch], 16 KB, chunk-swizzled
    __shared__ ushort_t lB[128 * 64];   // [n][64ch],  16 KB, chunk-swizzled
    int t = threadIdx.x, lane = t & 63, wave = t >> 6;
    // XCD-aware decode: 4 oc-tiles of one (b,oh-pair) -> same XCD, contiguous
    int g = blockIdx.x;
    int xcd = g & 7, s = g >> 3;        // s in [0,224)
    int octile = s & 3, pl = s >> 2;    // pl in [0,56)
    int pair = xcd * 56 + pl;           // [0,448)
    int bb = pair / 28, ohp = pair % 28;
    int oh0 = ohp * 2, oc0 = octile * 128;
    int mrow = lane & 15, quad = lane >> 4;
    int wm = wave & 1, wn = wave >> 1;
    int ak = mrow & 7;                  // A swizzle key (row&7 == mrow&7)

    f32x4 acc[4][4] = {};
    for (int kt = 0; kt < 36; kt++) {
        int khw = kt >> 2, icc = kt & 3;
        int kh = khw / 3, kw = khw - kh * 3;
        int p = (kw == 1) ? 0 : 1;
        bool zh0 = (oh0 == 0) && (kh == 0);        // r=-1: zero half 0
        int ldsShift = (kw == 0) ? 128 : 0;        // row0 holds w2=-1 zeros
        __syncthreads();
        if (zh0) {
            int4 z = {0, 0, 0, 0};
            *(int4*)(lB + t * 8) = z;
            *(int4*)(lB + 2048 + t * 8) = z;
        }
        if (kw == 0 && t < 16) {                   // zero w2=-1 row, both halves
            int4 z = {0, 0, 0, 0};
            *(int4*)(lB + (t >> 3) * 4096 + (t & 7) * 8) = z;
        }
        // --- A: 16 KB contiguous slab, 4 DMA per wave ---
        const char* asrc = (const char*)wds2
            + ((size_t)kt * 32768 + (size_t)oc0 * 64) * 2 + lane * 16;
#pragma unroll
        for (int i = 0; i < 4; i++) {
            int j = wave * 4 + i;
            gl_lds16(asrc + j * 1024, (char*)lA + j * 1024);
        }
        // --- B: two 7 KB row-slabs, 14 DMA round-robin over waves ---
        for (int j = wave; j < 14; j += 4) {
            int osub = (j >= 7) ? 1 : 0, jj = j - osub * 7;
            if (zh0 && osub == 0) continue;
            int r = 2 * oh0 + 2 * osub + kh - 1;   // 0..111 here
            const char* bsrc = (const char*)comb
                + ((size_t)bb * C_B + (size_t)r * C_H + (size_t)p * C_P
                   + (size_t)icc * C_I) * 2 + jj * 1024 + lane * 16;
            gl_lds16(bsrc, (char*)lB + osub * 8192 + ldsShift + jj * 1024);
        }
        __syncthreads();
        // --- frags + MFMA: wave (wm,wn) computes 64oc x 64n ---
        int bk = (mrow + ((kw == 0) ? 7 : 0)) & 7; // B swizzle key
#pragma unroll
        for (int ks = 0; ks < 2; ks++) {
            bf16x8 af[4], bf[4];
#pragma unroll
            for (int m = 0; m < 4; m++) {
                int row = wm * 64 + m * 16 + mrow;
                int ph = (ks * 4 + quad) ^ ak;
                af[m] = *(const bf16x8*)(lA + row * 64 + ph * 8);
            }
#pragma unroll
            for (int n = 0; n < 4; n++) {
                int nr = wn * 64 + n * 16 + mrow;
                int ph = (ks * 4 + quad) ^ bk;
                bf[n] = *(const bf16x8*)(lB + nr * 64 + ph * 8);
            }
#pragma unroll
            for (int m = 0; m < 4; m++)
#pragma unroll
                for (int n = 0; n < 4; n++)
                    acc[m][n] = __builtin_amdgcn_mfma_f32_16x16x32_bf16(
                        af[m], bf[n], acc[m][n], 0, 0, 0);
        }
    }
    // --- epilogue: BN2 + ReLU; D row=oc (quad*4+r), col=n (mrow) ---
#pragma unroll
    for (int m = 0; m < 4; m++) {
#pragma unroll
        for (int r4 = 0; r4 < 4; r4++) {
            int oc = oc0 + wm * 64 + m * 16 + quad * 4 + r4;
            float al = a2[oc], be = b2[oc];
#pragma unroll
            for (int n = 0; n < 4; n++) {
                int nr = wn * 64 + n * 16 + mrow;
                int osub = nr >> 6, ow = nr & 63;
                if (ow < OWn) {
                    float v = fmaxf(acc[m][n][r4] * al + be, 0.f);
                    out[((size_t)(bb * OCn + oc) * OHn + (oh0 + osub)) * OWn + ow] = v;
                }
            }
        }
    }
}

// ------------------------- launch ------------------------------------------
extern "C" void kernel_launch(void* const* d_in, const int* in_sizes, int n_in,
                              void* d_out, int out_size, void* d_ws, size_t ws_size,
                              hipStream_t stream) {
    const float* x     = (const float*)d_in[0];
    const float* wkg   = (const float*)d_in[1];
    const float* gdw_w = (const float*)d_in[2];
    const float* gdw_b = (const float*)d_in[3];
    const float* gpw_w = (const float*)d_in[4];
    const float* gpw_b = (const float*)d_in[5];
    const float* bn1g  = (const float*)d_in[6];
    const float* bn1b  = (const float*)d_in[7];
    const float* bn1m  = (const float*)d_in[8];
    const float* bn1v  = (const float*)d_in[9];
    const float* dsw   = (const float*)d_in[10];
    const float* dsb   = (const float*)d_in[11];
    const float* bn2g  = (const float*)d_in[12];
    const float* bn2b  = (const float*)d_in[13];
    const float* bn2m  = (const float*)d_in[14];
    const float* bn2v  = (const float*)d_in[15];

    // workspace layout (bytes). PROVEN footprint.
    char* ws = (char*)d_ws;
    float*    pooled = (float*)(ws + 0);           //  2048 f32 (sums)
    float*    kgen   = (float*)(ws + 8192);        // 18432 f32 (tap-major)
    float*    a1     = (float*)(ws + 81920);       //  128 f32
    float*    b1     = (float*)(ws + 82432);
    float*    a2     = (float*)(ws + 82944);       //  512 f32
    float*    b2     = (float*)(ws + 84992);
    ushort_t* gpwbf  = (ushort_t*)(ws + 87040);    // 16384 bf16 [87040,119808)
    ushort_t* wds2   = (ushort_t*)(ws + 119808);   // 36*512*64 bf16 (2.36 MB)
    ushort_t* comb   = (ushort_t*)(ws + 2479104);  // 102,760,448 B
    // xT (NHWC bf16 copy of x) lives in d_out: exactly 102,760,448 B, consumed
    // by k_dw before k_ds overwrites d_out with the real output.
    ushort_t* xT  = (ushort_t*)d_out;
    float*    out = (float*)d_out;

    k_wds <<<4608, 256, 0, stream>>>(dsw, wds2, gpw_w, gpw_b,
                                     bn1g, bn1b, bn1m, bn1v, dsb,
                                     bn2g, bn2b, bn2m, bn2v,
                                     gpwbf, a1, b1, a2, b2, pooled);
    k_xt  <<<1792, 256, 0, stream>>>(x, xT, pooled);
    k_kgen<<<72, 256, 0, stream>>>(pooled, wkg, kgen);
    k_dw  <<<dim3(Hh, Bn * 2), 256, 0, stream>>>(xT, kgen, gdw_w, gdw_b, comb);
    k_pw  <<<dim3(Hh, Bn), 256, 0, stream>>>(comb, gpwbf, a1, b1);
    k_ds  <<<1792, 256, 0, stream>>>(comb, wds2, a2, b2, out);
}